// Round 2
// baseline (1272.988 us; speedup 1.0000x reference)
//
#include <hip/hip_runtime.h>

// Problem constants
#define NROWS 65536   // 64*64*32*32 / 64
#define KC    1024
#define DD    64

// Output layout (floats) in d_out
#define QOFF  0                     // quantized_st: 4194304
#define IOFF  4194304               // indices:        65536
#define WOFF  4259840               // new_weight:     65536
#define CSOFF 4325376               // cs:              1024
#define EAOFF 4326400               // new_embed_avg:  65536

// Workspace layout (floats)
#define WS_CODESQ 0        // 1024
#define WS_COUNTS 1024     // 1024
#define WS_DW     2048     // 65536
#define WS_CSFIN  67584    // 1024

__device__ __forceinline__ float rowsq_np(const float* __restrict__ x) {
    // Replicates numpy pairwise_sum for n=64 over m[i] = fl(x[i]*x[i]):
    // r[j] = m[j] + m[8+j] + ... + m[56+j] (sequential), then
    // ((r0+r1)+(r2+r3)) + ((r4+r5)+(r6+r7)). No FMA contraction allowed.
    float r[8];
#pragma unroll
    for (int j = 0; j < 8; ++j) r[j] = __fmul_rn(x[j], x[j]);
#pragma unroll
    for (int i = 8; i < 64; i += 8) {
#pragma unroll
        for (int j = 0; j < 8; ++j)
            r[j] = __fadd_rn(r[j], __fmul_rn(x[i + j], x[i + j]));
    }
    float s01 = __fadd_rn(r[0], r[1]);
    float s23 = __fadd_rn(r[2], r[3]);
    float s45 = __fadd_rn(r[4], r[5]);
    float s67 = __fadd_rn(r[6], r[7]);
    return __fadd_rn(__fadd_rn(s01, s23), __fadd_rn(s45, s67));
}

// ---- Kernel A: code_sq[k] = sum_d w[k][d]^2 (numpy pairwise order) ----
__global__ void code_sq_kernel(const float* __restrict__ weight,
                               float* __restrict__ code_sq) {
    int c = blockIdx.x * blockDim.x + threadIdx.x;
    if (c >= KC) return;
    float wv[64];
    const float4* pw = reinterpret_cast<const float4*>(weight + (size_t)c * DD);
#pragma unroll
    for (int i = 0; i < 16; ++i) {
        float4 v = pw[i];
        wv[4 * i] = v.x; wv[4 * i + 1] = v.y; wv[4 * i + 2] = v.z; wv[4 * i + 3] = v.w;
    }
    code_sq[c] = rowsq_np(wv);
}

// ---- Kernel B: distances + argmin + quantized + indices + counts + dw ----
// 512 blocks x 512 threads (8 waves). Block handles 128 rows.
// Lane l (any wave) owns rows 2l, 2l+1 (x kept in VGPRs).
// Wave s scans codes {tile*128 + s*16 + kk}, kk in [0,16) -> LDS broadcast.
// K-split by 8 gives 4096 waves total = 16 waves/CU = 50% occupancy.
__global__ __launch_bounds__(512, 4) void vq_main(
    const float* __restrict__ x_in, const float* __restrict__ weight,
    const float* __restrict__ code_sq, float* __restrict__ out,
    float* __restrict__ counts, float* __restrict__ dw) {

    __shared__ float lds_w[128 * 64];     // 32 KB weight tile
    __shared__ float lds_csq[128];
    __shared__ float s_best[8 * 128];
    __shared__ int   s_bidx[8 * 128];
    __shared__ int   idx_lds[128];

    const int tid  = threadIdx.x;
    const int lane = tid & 63;
    const int wv   = tid >> 6;            // wave id 0..7 = K-split

    const size_t row0 = (size_t)blockIdx.x * 128 + 2 * lane;

    // Load 2 rows of x into registers (128 floats)
    float x0[64], x1[64];
    const float4* px = reinterpret_cast<const float4*>(x_in + row0 * DD);
#pragma unroll
    for (int i = 0; i < 16; ++i) {
        float4 v = px[i];
        x0[4 * i] = v.x; x0[4 * i + 1] = v.y; x0[4 * i + 2] = v.z; x0[4 * i + 3] = v.w;
    }
#pragma unroll
    for (int i = 0; i < 16; ++i) {
        float4 v = px[16 + i];
        x1[4 * i] = v.x; x1[4 * i + 1] = v.y; x1[4 * i + 2] = v.z; x1[4 * i + 3] = v.w;
    }

    const float rs0 = rowsq_np(x0);
    const float rs1 = rowsq_np(x1);

    float best0 = INFINITY, best1 = INFINITY;
    int bidx0 = 0, bidx1 = 0;

    for (int t = 0; t < KC / 128; ++t) {
        __syncthreads();
        // Stage 128-code weight tile (8192 floats = 2048 float4) + code_sq
        const float4* wsrc = reinterpret_cast<const float4*>(weight + (size_t)t * 128 * DD);
        float4* ldst = reinterpret_cast<float4*>(lds_w);
#pragma unroll
        for (int j = 0; j < 4; ++j) ldst[tid + j * 512] = wsrc[tid + j * 512];
        if (tid < 128) lds_csq[tid] = code_sq[t * 128 + tid];
        __syncthreads();

#pragma unroll 2
        for (int kk = 0; kk < 16; ++kk) {
            const int kl = wv * 16 + kk;
            const float* wrow = lds_w + kl * 64;
            float a00 = 0.f, a01 = 0.f, a02 = 0.f, a03 = 0.f;
            float a10 = 0.f, a11 = 0.f, a12 = 0.f, a13 = 0.f;
#pragma unroll
            for (int d = 0; d < 64; d += 4) {
                float4 w4 = *reinterpret_cast<const float4*>(wrow + d); // broadcast
                a00 += x0[d]     * w4.x;  a01 += x0[d + 1] * w4.y;
                a02 += x0[d + 2] * w4.z;  a03 += x0[d + 3] * w4.w;
                a10 += x1[d]     * w4.x;  a11 += x1[d + 1] * w4.y;
                a12 += x1[d + 2] * w4.z;  a13 += x1[d + 3] * w4.w;
            }
            float dot0 = (a00 + a01) + (a02 + a03);
            float dot1 = (a10 + a11) + (a12 + a13);
            float csq  = lds_csq[kl];
            // dist = fl(fl(rs + csq) - 2*dot)  (2*dot is exact)
            float d0 = __fsub_rn(__fadd_rn(rs0, csq), __fmul_rn(2.0f, dot0));
            float d1 = __fsub_rn(__fadd_rn(rs1, csq), __fmul_rn(2.0f, dot1));
            int kg = t * 128 + kl;
            if (d0 < best0) { best0 = d0; bidx0 = kg; }
            if (d1 < best1) { best1 = d1; bidx1 = kg; }
        }
    }

    // Publish per-wave candidates
    s_best[wv * 128 + 2 * lane]     = best0;
    s_best[wv * 128 + 2 * lane + 1] = best1;
    s_bidx[wv * 128 + 2 * lane]     = bidx0;
    s_bidx[wv * 128 + 2 * lane + 1] = bidx1;
    __syncthreads();

    // Wave 0 combines (lexicographic: min value, then min index)
    if (wv == 0) {
#pragma unroll
        for (int rr = 0; rr < 2; ++rr) {
            int rl = 2 * lane + rr;
            float bvv = s_best[rl];
            int   bii = s_bidx[rl];
#pragma unroll
            for (int s = 1; s < 8; ++s) {
                float v = s_best[s * 128 + rl];
                int   i = s_bidx[s * 128 + rl];
                if (v < bvv || (v == bvv && i < bii)) { bvv = v; bii = i; }
            }
            size_t grow = (size_t)blockIdx.x * 128 + rl;
            out[IOFF + grow] = (float)bii;
            atomicAdd(&counts[bii], 1.0f);
            idx_lds[rl] = bii;
        }
    }
    __syncthreads();

    // Epilogue: quantized_st + dw atomics. Block region = 128 rows * 64 d
    // = 2048 float4 over 512 threads = 4 each. Coalesced, L2-hot x re-read.
    const size_t blk_f4 = (size_t)blockIdx.x * 2048;
    const float4* xin4 = reinterpret_cast<const float4*>(x_in);
    float4* q4 = reinterpret_cast<float4*>(out + QOFF);
#pragma unroll
    for (int j = 0; j < 4; ++j) {
        int f4i = tid + j * 512;
        int fpos = f4i * 4;
        int rl = fpos >> 6;
        int d0 = fpos & 63;
        int idx = idx_lds[rl];
        float4 xv = xin4[blk_f4 + f4i];
        float4 wvv = *reinterpret_cast<const float4*>(weight + (size_t)idx * DD + d0);
        float4 qv;
        qv.x = __fadd_rn(xv.x, __fsub_rn(wvv.x, xv.x));
        qv.y = __fadd_rn(xv.y, __fsub_rn(wvv.y, xv.y));
        qv.z = __fadd_rn(xv.z, __fsub_rn(wvv.z, xv.z));
        qv.w = __fadd_rn(xv.w, __fsub_rn(wvv.w, xv.w));
        q4[blk_f4 + f4i] = qv;
        float* dwp = dw + (size_t)idx * DD + d0;
        atomicAdd(dwp + 0, xv.x);
        atomicAdd(dwp + 1, xv.y);
        atomicAdd(dwp + 2, xv.z);
        atomicAdd(dwp + 3, xv.w);
    }
}

// ---- Kernel C: cs update + normalize (needs n = sum cs) ----
__global__ void finalize_cs(const float* __restrict__ cluster_size,
                            const float* __restrict__ counts,
                            float* __restrict__ out,
                            float* __restrict__ cs_fin) {
    __shared__ float sb[1024];
    int k = threadIdx.x;
    float c = 0.99f * cluster_size[k] + 0.01f * counts[k];
    sb[k] = c;
    __syncthreads();
    for (int off = 512; off > 0; off >>= 1) {
        if (k < off) sb[k] += sb[k + off];
        __syncthreads();
    }
    float n = sb[0];
    float v = ((c + 1e-5f) / (n + 0.01024f)) * n;
    out[CSOFF + k] = v;
    cs_fin[k] = v;
}

// ---- Kernel D: EMA embed_avg + new weights ----
__global__ void finalize_w(const float* __restrict__ embed_avg,
                           const float* __restrict__ dw,
                           const float* __restrict__ cs_fin,
                           float* __restrict__ out) {
    int e = blockIdx.x * blockDim.x + threadIdx.x;
    if (e >= KC * DD) return;
    float na = 0.99f * embed_avg[e] + 0.01f * dw[e];
    float nw = na / cs_fin[e >> 6];
    out[EAOFF + e] = na;
    out[WOFF + e] = nw;
}

extern "C" void kernel_launch(void* const* d_in, const int* in_sizes, int n_in,
                              void* d_out, int out_size, void* d_ws, size_t ws_size,
                              hipStream_t stream) {
    (void)in_sizes; (void)n_in; (void)out_size; (void)ws_size;
    const float* x       = (const float*)d_in[0];
    const float* weight  = (const float*)d_in[1];
    const float* cluster = (const float*)d_in[2];
    const float* eavg    = (const float*)d_in[3];
    float* out = (float*)d_out;
    float* wsf = (float*)d_ws;

    float* code_sq = wsf + WS_CODESQ;
    float* counts  = wsf + WS_COUNTS;
    float* dwbuf   = wsf + WS_DW;
    float* cs_fin  = wsf + WS_CSFIN;

    // zero counts + dw (contiguous region)
    hipMemsetAsync(counts, 0, (size_t)(1024 + 65536) * sizeof(float), stream);

    hipLaunchKernelGGL(code_sq_kernel, dim3(4), dim3(256), 0, stream, weight, code_sq);
    hipLaunchKernelGGL(vq_main, dim3(512), dim3(512), 0, stream,
                       x, weight, code_sq, out, counts, dwbuf);
    hipLaunchKernelGGL(finalize_cs, dim3(1), dim3(1024), 0, stream,
                       cluster, counts, out, cs_fin);
    hipLaunchKernelGGL(finalize_w, dim3(256), dim3(256), 0, stream,
                       eavg, dwbuf, cs_fin, out);
}

// Round 3
// 194.297 us; speedup vs baseline: 6.5517x; 6.5517x over previous
//
#include <hip/hip_runtime.h>

// Problem constants
#define NROWS 65536   // 64*64*32*32 / 64
#define KC    1024
#define DD    64

// Output layout (floats) in d_out
#define QOFF  0                     // quantized_st: 4194304
#define IOFF  4194304               // indices:        65536
#define WOFF  4259840               // new_weight:     65536
#define CSOFF 4325376               // cs:              1024
#define EAOFF 4326400               // new_embed_avg:  65536

// Workspace layout (floats)
#define WS_CODESQ 0        // 1024
#define WS_COUNTS 1024     // 1024
#define WS_DW     2048     // 65536
#define WS_CSFIN  67584    // 1024

__device__ __forceinline__ float rowsq_np(const float* __restrict__ x) {
    // Replicates numpy pairwise_sum for n=64 over m[i] = fl(x[i]*x[i]).
    float r[8];
#pragma unroll
    for (int j = 0; j < 8; ++j) r[j] = __fmul_rn(x[j], x[j]);
#pragma unroll
    for (int i = 8; i < 64; i += 8) {
#pragma unroll
        for (int j = 0; j < 8; ++j)
            r[j] = __fadd_rn(r[j], __fmul_rn(x[i + j], x[i + j]));
    }
    float s01 = __fadd_rn(r[0], r[1]);
    float s23 = __fadd_rn(r[2], r[3]);
    float s45 = __fadd_rn(r[4], r[5]);
    float s67 = __fadd_rn(r[6], r[7]);
    return __fadd_rn(__fadd_rn(s01, s23), __fadd_rn(s45, s67));
}

// ---- Kernel A: code_sq[k] = sum_d w[k][d]^2 (numpy pairwise order) ----
__global__ void code_sq_kernel(const float* __restrict__ weight,
                               float* __restrict__ code_sq) {
    int c = blockIdx.x * blockDim.x + threadIdx.x;
    if (c >= KC) return;
    float wv[64];
    const float4* pw = reinterpret_cast<const float4*>(weight + (size_t)c * DD);
#pragma unroll
    for (int i = 0; i < 16; ++i) {
        float4 v = pw[i];
        wv[4 * i] = v.x; wv[4 * i + 1] = v.y; wv[4 * i + 2] = v.z; wv[4 * i + 3] = v.w;
    }
    code_sq[c] = rowsq_np(wv);
}

// ---- Kernel B: distances + argmin + quantized + indices + counts + dw ----
// 512 blocks x 256 threads (4 waves). Block handles 128 rows.
// Lane l owns rows 2l, 2l+1 (x in VGPRs). Wave wv scans codes
// [wv*256, wv*256+256) reading weight rows DIRECTLY from global via a
// wave-uniform pointer (readfirstlane) -> s_load / broadcast VMEM, no LDS.
__global__ __launch_bounds__(256, 2) void vq_main(
    const float* __restrict__ x_in, const float* __restrict__ weight,
    const float* __restrict__ code_sq, float* __restrict__ out,
    float* __restrict__ counts, float* __restrict__ dw) {

    __shared__ float s_best[4 * 128];
    __shared__ int   s_bidx[4 * 128];
    __shared__ int   idx_lds[128];

    const int tid  = threadIdx.x;
    const int lane = tid & 63;
    // Wave id, made provably wave-uniform for the compiler.
    const int wvu  = __builtin_amdgcn_readfirstlane(tid >> 6);

    const size_t row0 = (size_t)blockIdx.x * 128 + 2 * lane;

    // Load 2 rows of x into registers (128 floats)
    float x0[64], x1[64];
    const float4* px = reinterpret_cast<const float4*>(x_in + row0 * DD);
#pragma unroll
    for (int i = 0; i < 16; ++i) {
        float4 v = px[i];
        x0[4 * i] = v.x; x0[4 * i + 1] = v.y; x0[4 * i + 2] = v.z; x0[4 * i + 3] = v.w;
    }
#pragma unroll
    for (int i = 0; i < 16; ++i) {
        float4 v = px[16 + i];
        x1[4 * i] = v.x; x1[4 * i + 1] = v.y; x1[4 * i + 2] = v.z; x1[4 * i + 3] = v.w;
    }

    const float rs0 = rowsq_np(x0);
    const float rs1 = rowsq_np(x1);

    float best0 = INFINITY, best1 = INFINITY;
    int bidx0 = 0, bidx1 = 0;

    // Wave-uniform bases into weight / code_sq for this wave's K-slice.
    const float* __restrict__ wbase = weight + (size_t)wvu * 256 * DD;
    const float* __restrict__ cbase = code_sq + wvu * 256;

#pragma unroll 2
    for (int k = 0; k < 256; ++k) {
        const float4* wrow4 = reinterpret_cast<const float4*>(wbase + (size_t)k * DD);
        float4 wr[16];
#pragma unroll
        for (int i = 0; i < 16; ++i) wr[i] = wrow4[i];   // uniform addr: s_load/broadcast
        float csq = cbase[k];

        float a00 = 0.f, a01 = 0.f, a02 = 0.f, a03 = 0.f;
        float a10 = 0.f, a11 = 0.f, a12 = 0.f, a13 = 0.f;
#pragma unroll
        for (int d4 = 0; d4 < 16; ++d4) {
            float4 w4 = wr[d4];
            int d = d4 * 4;
            a00 += x0[d]     * w4.x;  a01 += x0[d + 1] * w4.y;
            a02 += x0[d + 2] * w4.z;  a03 += x0[d + 3] * w4.w;
            a10 += x1[d]     * w4.x;  a11 += x1[d + 1] * w4.y;
            a12 += x1[d + 2] * w4.z;  a13 += x1[d + 3] * w4.w;
        }
        float dot0 = (a00 + a01) + (a02 + a03);
        float dot1 = (a10 + a11) + (a12 + a13);
        // dist = fl(fl(rs + csq) - 2*dot)  (2*dot is exact)
        float d0 = __fsub_rn(__fadd_rn(rs0, csq), __fmul_rn(2.0f, dot0));
        float d1 = __fsub_rn(__fadd_rn(rs1, csq), __fmul_rn(2.0f, dot1));
        int kg = wvu * 256 + k;
        if (d0 < best0) { best0 = d0; bidx0 = kg; }
        if (d1 < best1) { best1 = d1; bidx1 = kg; }
    }

    // Publish per-wave candidates
    s_best[wvu * 128 + 2 * lane]     = best0;
    s_best[wvu * 128 + 2 * lane + 1] = best1;
    s_bidx[wvu * 128 + 2 * lane]     = bidx0;
    s_bidx[wvu * 128 + 2 * lane + 1] = bidx1;
    __syncthreads();

    // Wave 0 combines (lexicographic: min value, then min index; K-slices
    // are in ascending order across waves so value-tie -> lower wave wins)
    if (wvu == 0) {
#pragma unroll
        for (int rr = 0; rr < 2; ++rr) {
            int rl = 2 * lane + rr;
            float bvv = s_best[rl];
            int   bii = s_bidx[rl];
#pragma unroll
            for (int s = 1; s < 4; ++s) {
                float v = s_best[s * 128 + rl];
                int   i = s_bidx[s * 128 + rl];
                if (v < bvv || (v == bvv && i < bii)) { bvv = v; bii = i; }
            }
            size_t grow = (size_t)blockIdx.x * 128 + rl;
            out[IOFF + grow] = (float)bii;
            atomicAdd(&counts[bii], 1.0f);
            idx_lds[rl] = bii;
        }
    }
    __syncthreads();

    // Epilogue: quantized_st + dw atomics. Block region = 128 rows * 64 d
    // = 2048 float4 over 256 threads = 8 each. Coalesced, L2-hot x re-read.
    const size_t blk_f4 = (size_t)blockIdx.x * 2048;
    const float4* xin4 = reinterpret_cast<const float4*>(x_in);
    float4* q4 = reinterpret_cast<float4*>(out + QOFF);
#pragma unroll
    for (int j = 0; j < 8; ++j) {
        int f4i = tid + j * 256;
        int fpos = f4i * 4;
        int rl = fpos >> 6;
        int d0 = fpos & 63;
        int idx = idx_lds[rl];
        float4 xv = xin4[blk_f4 + f4i];
        float4 wvv = *reinterpret_cast<const float4*>(weight + (size_t)idx * DD + d0);
        float4 qv;
        qv.x = __fadd_rn(xv.x, __fsub_rn(wvv.x, xv.x));
        qv.y = __fadd_rn(xv.y, __fsub_rn(wvv.y, xv.y));
        qv.z = __fadd_rn(xv.z, __fsub_rn(wvv.z, xv.z));
        qv.w = __fadd_rn(xv.w, __fsub_rn(wvv.w, xv.w));
        q4[blk_f4 + f4i] = qv;
        float* dwp = dw + (size_t)idx * DD + d0;
        atomicAdd(dwp + 0, xv.x);
        atomicAdd(dwp + 1, xv.y);
        atomicAdd(dwp + 2, xv.z);
        atomicAdd(dwp + 3, xv.w);
    }
}

// ---- Kernel C: cs update + normalize (needs n = sum cs) ----
__global__ void finalize_cs(const float* __restrict__ cluster_size,
                            const float* __restrict__ counts,
                            float* __restrict__ out,
                            float* __restrict__ cs_fin) {
    __shared__ float sb[1024];
    int k = threadIdx.x;
    float c = 0.99f * cluster_size[k] + 0.01f * counts[k];
    sb[k] = c;
    __syncthreads();
    for (int off = 512; off > 0; off >>= 1) {
        if (k < off) sb[k] += sb[k + off];
        __syncthreads();
    }
    float n = sb[0];
    float v = ((c + 1e-5f) / (n + 0.01024f)) * n;
    out[CSOFF + k] = v;
    cs_fin[k] = v;
}

// ---- Kernel D: EMA embed_avg + new weights ----
__global__ void finalize_w(const float* __restrict__ embed_avg,
                           const float* __restrict__ dw,
                           const float* __restrict__ cs_fin,
                           float* __restrict__ out) {
    int e = blockIdx.x * blockDim.x + threadIdx.x;
    if (e >= KC * DD) return;
    float na = 0.99f * embed_avg[e] + 0.01f * dw[e];
    float nw = na / cs_fin[e >> 6];
    out[EAOFF + e] = na;
    out[WOFF + e] = nw;
}

extern "C" void kernel_launch(void* const* d_in, const int* in_sizes, int n_in,
                              void* d_out, int out_size, void* d_ws, size_t ws_size,
                              hipStream_t stream) {
    (void)in_sizes; (void)n_in; (void)out_size; (void)ws_size;
    const float* x       = (const float*)d_in[0];
    const float* weight  = (const float*)d_in[1];
    const float* cluster = (const float*)d_in[2];
    const float* eavg    = (const float*)d_in[3];
    float* out = (float*)d_out;
    float* wsf = (float*)d_ws;

    float* code_sq = wsf + WS_CODESQ;
    float* counts  = wsf + WS_COUNTS;
    float* dwbuf   = wsf + WS_DW;
    float* cs_fin  = wsf + WS_CSFIN;

    // zero counts + dw (contiguous region)
    hipMemsetAsync(counts, 0, (size_t)(1024 + 65536) * sizeof(float), stream);

    hipLaunchKernelGGL(code_sq_kernel, dim3(4), dim3(256), 0, stream, weight, code_sq);
    hipLaunchKernelGGL(vq_main, dim3(512), dim3(256), 0, stream,
                       x, weight, code_sq, out, counts, dwbuf);
    hipLaunchKernelGGL(finalize_cs, dim3(1), dim3(1024), 0, stream,
                       cluster, counts, out, cs_fin);
    hipLaunchKernelGGL(finalize_w, dim3(256), dim3(256), 0, stream,
                       eavg, dwbuf, cs_fin, out);
}

// Round 5
// 170.504 us; speedup vs baseline: 7.4660x; 1.1395x over previous
//
#include <hip/hip_runtime.h>

// Problem constants
#define NROWS 65536   // 64*64*32*32 / 64
#define KC    1024
#define DD    64

// Output layout (floats) in d_out
#define QOFF  0                     // quantized_st: 4194304
#define IOFF  4194304               // indices:        65536
#define WOFF  4259840               // new_weight:     65536
#define CSOFF 4325376               // cs:              1024
#define EAOFF 4326400               // new_embed_avg:  65536

// Workspace layout (floats)
#define WS_CODESQ 0        // 1024
#define WS_COUNTS 1024     // 1024
#define WS_DW     2048     // 65536
#define WS_CSFIN  67584    // 1024

// POD 4-float vector usable through address_space(4) pointers (no HIP
// vector-type constructors involved -> plain AS(4) load).
struct F4 { float x, y, z, w; };
typedef const __attribute__((address_space(4))) F4    c4F4;
typedef const __attribute__((address_space(4))) float c4f;

__device__ __forceinline__ float rowsq_np(const float* __restrict__ x) {
    // numpy pairwise_sum for n=64 over m[i] = fl(x[i]*x[i]).
    float r[8];
#pragma unroll
    for (int j = 0; j < 8; ++j) r[j] = __fmul_rn(x[j], x[j]);
#pragma unroll
    for (int i = 8; i < 64; i += 8) {
#pragma unroll
        for (int j = 0; j < 8; ++j)
            r[j] = __fadd_rn(r[j], __fmul_rn(x[i + j], x[i + j]));
    }
    float s01 = __fadd_rn(r[0], r[1]);
    float s23 = __fadd_rn(r[2], r[3]);
    float s45 = __fadd_rn(r[4], r[5]);
    float s67 = __fadd_rn(r[6], r[7]);
    return __fadd_rn(__fadd_rn(s01, s23), __fadd_rn(s45, s67));
}

// ---- Kernel A: code_sq[k] = sum_d w[k][d]^2 (numpy pairwise order) ----
__global__ void code_sq_kernel(const float* __restrict__ weight,
                               float* __restrict__ code_sq) {
    int c = blockIdx.x * blockDim.x + threadIdx.x;
    if (c >= KC) return;
    float wv[64];
    const float4* pw = reinterpret_cast<const float4*>(weight + (size_t)c * DD);
#pragma unroll
    for (int i = 0; i < 16; ++i) {
        float4 v = pw[i];
        wv[4 * i] = v.x; wv[4 * i + 1] = v.y; wv[4 * i + 2] = v.z; wv[4 * i + 3] = v.w;
    }
    code_sq[c] = rowsq_np(wv);
}

// ---- Kernel B: distances + argmin + quantized + indices + counts + dw ----
// 1024 blocks x 256 threads (4 waves). Block = 64 rows; lane l owns row l
// (x in 16 float4 VGPRs, ~90 VGPR total -> 4 waves/SIMD). Wave wv scans
// codes [wv*256, wv*256+256) reading weight rows through an addrspace(4)
// (constant) pointer with wave-uniform address -> s_load into SGPRs,
// consumed as the SGPR operand of v_fmac_f32. No LDS in the main loop.
__global__ __launch_bounds__(256, 4) void vq_main(
    const float* __restrict__ x_in, const float* __restrict__ weight,
    const float* __restrict__ code_sq, float* __restrict__ out,
    float* __restrict__ counts, float* __restrict__ dw) {

    __shared__ float s_best[4 * 64];
    __shared__ int   s_bidx[4 * 64];
    __shared__ int   idx_lds[64];

    const int tid  = threadIdx.x;
    const int lane = tid & 63;
    const int wvu  = __builtin_amdgcn_readfirstlane(tid >> 6);

    const size_t row = (size_t)blockIdx.x * 64 + lane;

    // Load this thread's row of x (64 floats) as 16 float4 values.
    float4 xv[16];
    const float4* px = reinterpret_cast<const float4*>(x_in + row * DD);
#pragma unroll
    for (int i = 0; i < 16; ++i) xv[i] = px[i];

    // rowsq in numpy pairwise order: even-i and odd-i float4 accumulators.
    float4 re, ro;
    re.x = __fmul_rn(xv[0].x, xv[0].x); re.y = __fmul_rn(xv[0].y, xv[0].y);
    re.z = __fmul_rn(xv[0].z, xv[0].z); re.w = __fmul_rn(xv[0].w, xv[0].w);
    ro.x = __fmul_rn(xv[1].x, xv[1].x); ro.y = __fmul_rn(xv[1].y, xv[1].y);
    ro.z = __fmul_rn(xv[1].z, xv[1].z); ro.w = __fmul_rn(xv[1].w, xv[1].w);
#pragma unroll
    for (int i = 2; i < 16; i += 2) {
        re.x = __fadd_rn(re.x, __fmul_rn(xv[i].x, xv[i].x));
        re.y = __fadd_rn(re.y, __fmul_rn(xv[i].y, xv[i].y));
        re.z = __fadd_rn(re.z, __fmul_rn(xv[i].z, xv[i].z));
        re.w = __fadd_rn(re.w, __fmul_rn(xv[i].w, xv[i].w));
        ro.x = __fadd_rn(ro.x, __fmul_rn(xv[i + 1].x, xv[i + 1].x));
        ro.y = __fadd_rn(ro.y, __fmul_rn(xv[i + 1].y, xv[i + 1].y));
        ro.z = __fadd_rn(ro.z, __fmul_rn(xv[i + 1].z, xv[i + 1].z));
        ro.w = __fadd_rn(ro.w, __fmul_rn(xv[i + 1].w, xv[i + 1].w));
    }
    const float rs = __fadd_rn(__fadd_rn(__fadd_rn(re.x, re.y), __fadd_rn(re.z, re.w)),
                               __fadd_rn(__fadd_rn(ro.x, ro.y), __fadd_rn(ro.z, ro.w)));

    // Wave-uniform constant-addrspace bases (built from readfirstlane'd
    // integer -> provably uniform, AS(4) -> scalar loads).
    unsigned long long wa = (unsigned long long)(weight + (size_t)wvu * 256 * DD);
    unsigned long long ca = (unsigned long long)(code_sq + wvu * 256);
    unsigned wal = __builtin_amdgcn_readfirstlane((unsigned)wa);
    unsigned wah = __builtin_amdgcn_readfirstlane((unsigned)(wa >> 32));
    unsigned cal = __builtin_amdgcn_readfirstlane((unsigned)ca);
    unsigned cah = __builtin_amdgcn_readfirstlane((unsigned)(ca >> 32));
    c4F4* wb4 = (c4F4*)(((unsigned long long)wah << 32) | wal);
    c4f*  cb  = (c4f*)(((unsigned long long)cah << 32) | cal);

    float best = INFINITY;
    int bidx = 0;

#pragma unroll 2
    for (int k = 0; k < 256; ++k) {
        float a0 = 0.f, a1 = 0.f, a2 = 0.f, a3 = 0.f;
#pragma unroll
        for (int i = 0; i < 16; ++i) {
            F4 w4;                         // plain POD copy from AS(4)
            w4.x = wb4[k * 16 + i].x;
            w4.y = wb4[k * 16 + i].y;
            w4.z = wb4[k * 16 + i].z;
            w4.w = wb4[k * 16 + i].w;
            a0 += xv[i].x * w4.x;
            a1 += xv[i].y * w4.y;
            a2 += xv[i].z * w4.z;
            a3 += xv[i].w * w4.w;
        }
        float dot = (a0 + a1) + (a2 + a3);
        float csq = cb[k];
        float dst = __fsub_rn(__fadd_rn(rs, csq), __fmul_rn(2.0f, dot));
        int kg = wvu * 256 + k;
        if (dst < best) { best = dst; bidx = kg; }
    }

    // Publish per-wave candidates (one row per lane).
    s_best[wvu * 64 + lane] = best;
    s_bidx[wvu * 64 + lane] = bidx;
    __syncthreads();

    // Wave 0 combines across the 4 K-slices (lexicographic min).
    if (wvu == 0) {
        float bvv = s_best[lane];
        int   bii = s_bidx[lane];
#pragma unroll
        for (int s = 1; s < 4; ++s) {
            float v = s_best[s * 64 + lane];
            int   i = s_bidx[s * 64 + lane];
            if (v < bvv || (v == bvv && i < bii)) { bvv = v; bii = i; }
        }
        size_t grow = (size_t)blockIdx.x * 64 + lane;
        out[IOFF + grow] = (float)bii;
        atomicAdd(&counts[bii], 1.0f);
        idx_lds[lane] = bii;
    }
    __syncthreads();

    // Epilogue: quantized_st + dw atomics. Block region = 64 rows * 64 d
    // = 1024 float4 over 256 threads = 4 each. Coalesced, L2-hot x re-read.
    const size_t blk_f4 = (size_t)blockIdx.x * 1024;
    const float4* xin4 = reinterpret_cast<const float4*>(x_in);
    const float4* w4g  = reinterpret_cast<const float4*>(weight);
    float4* q4 = reinterpret_cast<float4*>(out + QOFF);
#pragma unroll
    for (int j = 0; j < 4; ++j) {
        int f4i = tid + j * 256;
        int rl  = f4i >> 4;          // row within block
        int d4  = f4i & 15;          // float4 index within row
        int idx = idx_lds[rl];
        float4 xq = xin4[blk_f4 + f4i];
        float4 wq = w4g[idx * 16 + d4];
        float4 qv;
        qv.x = __fadd_rn(xq.x, __fsub_rn(wq.x, xq.x));
        qv.y = __fadd_rn(xq.y, __fsub_rn(wq.y, xq.y));
        qv.z = __fadd_rn(xq.z, __fsub_rn(wq.z, xq.z));
        qv.w = __fadd_rn(xq.w, __fsub_rn(wq.w, xq.w));
        q4[blk_f4 + f4i] = qv;
        float* dwp = dw + (size_t)idx * DD + d4 * 4;
        atomicAdd(dwp + 0, xq.x);
        atomicAdd(dwp + 1, xq.y);
        atomicAdd(dwp + 2, xq.z);
        atomicAdd(dwp + 3, xq.w);
    }
}

// ---- Kernel C: cs update + normalize (needs n = sum cs) ----
__global__ void finalize_cs(const float* __restrict__ cluster_size,
                            const float* __restrict__ counts,
                            float* __restrict__ out,
                            float* __restrict__ cs_fin) {
    __shared__ float sb[1024];
    int k = threadIdx.x;
    float c = 0.99f * cluster_size[k] + 0.01f * counts[k];
    sb[k] = c;
    __syncthreads();
    for (int off = 512; off > 0; off >>= 1) {
        if (k < off) sb[k] += sb[k + off];
        __syncthreads();
    }
    float n = sb[0];
    float v = ((c + 1e-5f) / (n + 0.01024f)) * n;
    out[CSOFF + k] = v;
    cs_fin[k] = v;
}

// ---- Kernel D: EMA embed_avg + new weights ----
__global__ void finalize_w(const float* __restrict__ embed_avg,
                           const float* __restrict__ dw,
                           const float* __restrict__ cs_fin,
                           float* __restrict__ out) {
    int e = blockIdx.x * blockDim.x + threadIdx.x;
    if (e >= KC * DD) return;
    float na = 0.99f * embed_avg[e] + 0.01f * dw[e];
    float nw = na / cs_fin[e >> 6];
    out[EAOFF + e] = na;
    out[WOFF + e] = nw;
}

extern "C" void kernel_launch(void* const* d_in, const int* in_sizes, int n_in,
                              void* d_out, int out_size, void* d_ws, size_t ws_size,
                              hipStream_t stream) {
    (void)in_sizes; (void)n_in; (void)out_size; (void)ws_size;
    const float* x       = (const float*)d_in[0];
    const float* weight  = (const float*)d_in[1];
    const float* cluster = (const float*)d_in[2];
    const float* eavg    = (const float*)d_in[3];
    float* out = (float*)d_out;
    float* wsf = (float*)d_ws;

    float* code_sq = wsf + WS_CODESQ;
    float* counts  = wsf + WS_COUNTS;
    float* dwbuf   = wsf + WS_DW;
    float* cs_fin  = wsf + WS_CSFIN;

    // zero counts + dw (contiguous region)
    (void)hipMemsetAsync(counts, 0, (size_t)(1024 + 65536) * sizeof(float), stream);

    hipLaunchKernelGGL(code_sq_kernel, dim3(4), dim3(256), 0, stream, weight, code_sq);
    hipLaunchKernelGGL(vq_main, dim3(1024), dim3(256), 0, stream,
                       x, weight, code_sq, out, counts, dwbuf);
    hipLaunchKernelGGL(finalize_cs, dim3(1), dim3(1024), 0, stream,
                       cluster, counts, out, cs_fin);
    hipLaunchKernelGGL(finalize_w, dim3(256), dim3(256), 0, stream,
                       eavg, dwbuf, cs_fin, out);
}